// Round 6
// baseline (640.788 us; speedup 1.0000x reference)
//
#include <hip/hip_runtime.h>
#include <hip/hip_bf16.h>

#define N_TOK 4096
#define DIM   1024
#define H2V   4096
#define HV    2048
#define NE    8
#define BM    256
#define BN    128                // output cols per block (staged W cols = 2*BN = 256)
#define BK    64
#define NTHR  512
#define KSTEPS (DIM / BK)        // 16
#define CT_TILES (HV / BN)       // 16
#define RT_SLOTS (N_TOK / BM)    // 16 worst-case row tiles per expert
#define NPAIR (NE * CT_TILES)    // 128 (e,ct) pairs

// d_ws layout
#define WS_COUNTS 0
#define WS_BASE   64             // 9 ints
#define WS_SLOTS  128            // NE*N_TOK u16 = 64 KiB
#define WS_XPERM  66560          // N_TOK rows x DIM bf16 = 8.39 MB

typedef __attribute__((ext_vector_type(4))) float  f32x4;
typedef __attribute__((ext_vector_type(8))) short  s16x8;

__device__ __forceinline__ unsigned short f2bf(float f) {
    union { __hip_bfloat16 h; unsigned short u; } v;
    v.h = __float2bfloat16(f);
    return v.u;
}

__global__ void k_init(int* __restrict__ counts) {
    if (threadIdx.x < NE) counts[threadIdx.x] = 0;
}

__global__ void k_scatter(const int* __restrict__ idx, int* __restrict__ counts,
                          unsigned short* __restrict__ slots) {
    int n = blockIdx.x * blockDim.x + threadIdx.x;
    if (n < N_TOK) {
        int e = idx[n];
        int p = atomicAdd(&counts[e], 1);
        slots[e * N_TOK + p] = (unsigned short)n;
    }
}

__global__ void k_base(const int* __restrict__ counts, int* __restrict__ base) {
    if (threadIdx.x == 0) {
        int b = 0;
#pragma unroll
        for (int e = 0; e < NE; ++e) { base[e] = b; b += counts[e]; }
        base[NE] = b;
    }
}

// gather X rows into expert-sorted bf16 X_perm; 4 rows per block
__global__ void k_gather(const float* __restrict__ X, const int* __restrict__ base,
                         const unsigned short* __restrict__ slots,
                         unsigned short* __restrict__ Xp) {
    const int r    = blockIdx.x * 4 + (threadIdx.x >> 6);
    const int lane = threadIdx.x & 63;
    int e = 0;
#pragma unroll
    for (int i = 0; i < NE - 1; ++i) if (r >= base[i + 1]) e = i + 1;
    const int tok = slots[e * N_TOK + (r - base[e])];
    const float* src = X + (size_t)tok * DIM + lane * 16;
    unsigned short* dst = Xp + (size_t)r * DIM + lane * 16;
    f32x4 v0 = *(const f32x4*)(src);
    f32x4 v1 = *(const f32x4*)(src + 4);
    f32x4 v2 = *(const f32x4*)(src + 8);
    f32x4 v3 = *(const f32x4*)(src + 12);
    unsigned short t0[8], t1[8];
#pragma unroll
    for (int i = 0; i < 4; ++i) { t0[i] = f2bf(v0[i]); t0[4 + i] = f2bf(v1[i]); }
#pragma unroll
    for (int i = 0; i < 4; ++i) { t1[i] = f2bf(v2[i]); t1[4 + i] = f2bf(v3[i]); }
    *(s16x8*)(dst)     = *(const s16x8*)t0;
    *(s16x8*)(dst + 8) = *(const s16x8*)t1;
}

__global__ __launch_bounds__(NTHR, 4) void k_gemm(
        const float* __restrict__ W, const int* __restrict__ counts,
        const int* __restrict__ base, const unsigned short* __restrict__ slots,
        const unsigned short* __restrict__ Xp, float* __restrict__ out) {
    // XCD-paired 1-D grid: id = rt*NPAIR + (e*CT_TILES+ct); id%8 == ct%8, so all
    // row-tiles of one (e,ct) land on the SAME XCD, ~NPAIR/8 dispatch slots apart
    // -> their shared 1 MB W-tile stream stays L2-resident.
    const int bid = blockIdx.x;
    const int p   = bid & (NPAIR - 1);
    const int rt  = bid >> 7;           // log2(NPAIR)=7
    const int e   = p >> 4;             // log2(CT_TILES)=4
    const int ct  = p & (CT_TILES - 1);
    const int cnt = counts[e];
    const int tbase = rt * BM;
    if (tbase >= cnt) return;

    // As: [row][k] bf16, slot = q ^ (row&7), written via pre-swizzled global src +
    // linear global_load_lds. Bs: [col][k] bf16 transposed W, slot = ko ^ key(c).
    // Both single-buffered: 32 KiB + 32 KiB = 64 KiB -> 2 blocks/CU.
    __shared__ unsigned short As[BM * BK];
    __shared__ unsigned short Bs[2 * BN * BK];

    const int t    = threadIdx.x;
    const int lane = t & 63;
    const int wid  = t >> 6;            // 0..7
    const int wm   = wid >> 1;          // wave row 0..3 (64 rows each)
    const int wn   = wid & 1;           // wave col 0..1 (64 out-cols each)
    const int l16  = lane & 15;
    const int g16  = lane >> 4;

    // ---- A staging via global_load_lds: 4 instrs/thread, pre-swizzled source ----
    const unsigned short* aptr[4];
#pragma unroll
    for (int j = 0; j < 4; ++j) {
        int i  = wid * 4 + j;                       // 0..31 chunks of 1 KiB
        int rl = i * 8 + (lane >> 3);               // tile row 0..255
        int qs = (lane & 7) ^ ((lane >> 3) & 7);    // pre-swizzled k-granule
        int slot = tbase + rl;
        aptr[j] = Xp + (size_t)(base[e] + min(slot, cnt - 1)) * DIM + qs * 8;
    }
    // ---- B staging: per 256-thread half, cols 0..127 / 128..255; 8 dwordx4 ----
    const int c0 = (t & 31) * 4 + ((t >> 8) & 1) * 128;   // local col, 4 per thread
    const int ko = (t >> 5) & 7;                          // k-octet 0..7
    const int gcol = ct * BN + (c0 & 127) + (c0 >> 7) * HV;  // gate cols / up cols
    const float* bptr = W + (size_t)e * DIM * H2V + (size_t)(ko * 8) * H2V + gcol;

    f32x4 acc[2][4][4];
    const f32x4 zero = {0.f, 0.f, 0.f, 0.f};
#pragma unroll
    for (int g = 0; g < 2; ++g)
#pragma unroll
        for (int m = 0; m < 4; ++m)
#pragma unroll
            for (int n = 0; n < 4; ++n) acc[g][m][n] = zero;

    f32x4 bv[8];                        // single B register set (no spill)

    auto issueA = [&](int ks) {
#pragma unroll
        for (int j = 0; j < 4; ++j) {
            const unsigned short* g = aptr[j] + ks * BK;
            unsigned short* l = (unsigned short*)&As[(wid * 4 + j) * 512];
            __builtin_amdgcn_global_load_lds(
                (const __attribute__((address_space(1))) unsigned int*)(const void*)g,
                (__attribute__((address_space(3))) unsigned int*)(void*)l, 16, 0, 0);
        }
    };
    auto loadB = [&](int ks) {
#pragma unroll
        for (int i = 0; i < 8; ++i)
            bv[i] = *(const f32x4*)(bptr + (size_t)(ks * BK + i) * H2V);
    };
    auto storeB = [&]() {
#pragma unroll
        for (int j = 0; j < 4; ++j) {
            int c = c0 + j;
            int key = ((c >> 1) ^ (c >> 4)) & 7;
            unsigned short tmp[8];
#pragma unroll
            for (int i = 0; i < 8; ++i) tmp[i] = f2bf(bv[i][j]);
            *(s16x8*)&Bs[c * 64 + ((ko ^ key) * 8)] = *(const s16x8*)tmp;
        }
    };
    auto mfmaPhase = [&]() {
        __builtin_amdgcn_s_setprio(1);
#pragma unroll
        for (int kk = 0; kk < 2; ++kk) {
            const int gran = kk * 4 + g16;
            s16x8 af[4], bfr[2][4];
#pragma unroll
            for (int m = 0; m < 4; ++m) {
                int row = wm * 64 + m * 16 + l16;
                af[m] = *(const s16x8*)&As[row * 64 + ((gran ^ (row & 7)) * 8)];
            }
#pragma unroll
            for (int g = 0; g < 2; ++g)
#pragma unroll
                for (int n = 0; n < 4; ++n) {
                    int c = g * 128 + wn * 64 + n * 16 + l16;
                    int key = ((c >> 1) ^ (c >> 4)) & 7;
                    bfr[g][n] = *(const s16x8*)&Bs[c * 64 + ((gran ^ key) * 8)];
                }
#pragma unroll
            for (int g = 0; g < 2; ++g)
#pragma unroll
                for (int m = 0; m < 4; ++m)
#pragma unroll
                    for (int n = 0; n < 4; ++n)
                        acc[g][m][n] = __builtin_amdgcn_mfma_f32_16x16x32_bf16(
                            af[m], bfr[g][n], acc[g][m][n], 0, 0, 0);
        }
        __builtin_amdgcn_s_setprio(0);
    };

    // ---- prologue: A(0)+B(0) in flight; stage both; start B(1) ----
    issueA(0);
    loadB(0);
    asm volatile("s_waitcnt vmcnt(0)" ::: "memory");
    __builtin_amdgcn_sched_barrier(0);
    storeB();
    loadB(1);                           // 8 loads in flight across iter 0's MFMA
    asm volatile("s_waitcnt lgkmcnt(0)" ::: "memory");
    __builtin_amdgcn_sched_barrier(0);
    __builtin_amdgcn_s_barrier();

    // ---- main loop (single-buffered As/Bs; counted vmcnt, no mid-loop drain) ----
    // top-of-iter state: As=A(ks), Bs=B(ks) valid; B(ks+1)[8] in flight.
#pragma unroll 1
    for (int ks = 0; ks < KSTEPS; ++ks) {
        mfmaPhase();
        if (ks + 1 < KSTEPS) {
            __builtin_amdgcn_s_barrier();                      // all reads of As/Bs done
            issueA(ks + 1);                                    // 4 gll -> As
            asm volatile("s_waitcnt vmcnt(4)" ::: "memory");   // B(ks+1) regs landed
            __builtin_amdgcn_sched_barrier(0);
            storeB();                                          // -> Bs
            if (ks + 2 < KSTEPS) {
                loadB(ks + 2);                                 // window: barrier+mfma
                asm volatile("s_waitcnt vmcnt(8) lgkmcnt(0)" ::: "memory"); // A(ks+1) done
            } else {
                asm volatile("s_waitcnt vmcnt(0) lgkmcnt(0)" ::: "memory"); // tail: drain A
            }
            __builtin_amdgcn_sched_barrier(0);
            __builtin_amdgcn_s_barrier();                      // staging visible
        }
    }

    // epilogue: silu(gate) * up, scatter rows to token ids
    const unsigned short* ids = slots + e * N_TOK;
#pragma unroll
    for (int m = 0; m < 4; ++m) {
#pragma unroll
        for (int r = 0; r < 4; ++r) {
            int rowt = wm * 64 + m * 16 + g16 * 4 + r;         // C/D: row=(lane>>4)*4+r
            int slot = tbase + rowt;
            if (slot < cnt) {
                int tok = ids[slot];
#pragma unroll
                for (int n = 0; n < 4; ++n) {
                    int col = ct * BN + wn * 64 + n * 16 + l16;  // C/D: col=lane&15
                    float a = acc[0][m][n][r];
                    float b = acc[1][m][n][r];
                    float sg = a / (1.0f + __expf(-a));
                    out[(size_t)tok * HV + col] = sg * b;
                }
            }
        }
    }
}

extern "C" void kernel_launch(void* const* d_in, const int* in_sizes, int n_in,
                              void* d_out, int out_size, void* d_ws, size_t ws_size,
                              hipStream_t stream) {
    const float* X  = (const float*)d_in[0];
    const float* W  = (const float*)d_in[1];
    const int* idx  = (const int*)d_in[2];
    float* out      = (float*)d_out;

    int* counts = (int*)((char*)d_ws + WS_COUNTS);
    int* base   = (int*)((char*)d_ws + WS_BASE);
    unsigned short* slots = (unsigned short*)((char*)d_ws + WS_SLOTS);
    unsigned short* Xp    = (unsigned short*)((char*)d_ws + WS_XPERM);

    k_init<<<1, 64, 0, stream>>>(counts);
    k_scatter<<<N_TOK / 256, 256, 0, stream>>>(idx, counts, slots);
    k_base<<<1, 64, 0, stream>>>(counts, base);
    k_gather<<<N_TOK / 4, 256, 0, stream>>>(X, base, slots, Xp);
    k_gemm<<<RT_SLOTS * NPAIR, NTHR, 0, stream>>>(W, counts, base, slots, Xp, out);
}

// Round 7
// 111.583 us; speedup vs baseline: 5.7427x; 5.7427x over previous
//
#include <hip/hip_runtime.h>
#include <hip/hip_bf16.h>

#define N_TOK 4096
#define DIM   1024
#define H2V   4096
#define HV    2048
#define NE    8
#define BM    256
#define BN    128                // output cols per block (staged W cols = 2*BN = 256)
#define BK    64
#define NTHR  512
#define KSTEPS (DIM / BK)        // 16
#define CT_TILES (HV / BN)       // 16
#define RT_SLOTS (N_TOK / BM)    // 16 worst-case row tiles per expert
#define NPAIR (NE * CT_TILES)    // 128 (e,ct) pairs

// d_ws layout
#define WS_COUNTS 0
#define WS_BASE   64             // 9 ints
#define WS_SLOTS  128            // NE*N_TOK u16 = 64 KiB
#define WS_XPERM  66560          // N_TOK rows x DIM bf16 = 8.39 MB

typedef __attribute__((ext_vector_type(4))) float  f32x4;
typedef __attribute__((ext_vector_type(8))) short  s16x8;

__device__ __forceinline__ unsigned short f2bf(float f) {
    union { __hip_bfloat16 h; unsigned short u; } v;
    v.h = __float2bfloat16(f);
    return v.u;
}

__global__ void k_init(int* __restrict__ counts) {
    if (threadIdx.x < NE) counts[threadIdx.x] = 0;
}

__global__ void k_scatter(const int* __restrict__ idx, int* __restrict__ counts,
                          unsigned short* __restrict__ slots) {
    int n = blockIdx.x * blockDim.x + threadIdx.x;
    if (n < N_TOK) {
        int e = idx[n];
        int p = atomicAdd(&counts[e], 1);
        slots[e * N_TOK + p] = (unsigned short)n;
    }
}

__global__ void k_base(const int* __restrict__ counts, int* __restrict__ base) {
    if (threadIdx.x == 0) {
        int b = 0;
#pragma unroll
        for (int e = 0; e < NE; ++e) { base[e] = b; b += counts[e]; }
        base[NE] = b;
    }
}

// gather X rows into expert-sorted bf16 X_perm; 4 rows per block
__global__ void k_gather(const float* __restrict__ X, const int* __restrict__ base,
                         const unsigned short* __restrict__ slots,
                         unsigned short* __restrict__ Xp) {
    const int r    = blockIdx.x * 4 + (threadIdx.x >> 6);
    const int lane = threadIdx.x & 63;
    int e = 0;
#pragma unroll
    for (int i = 0; i < NE - 1; ++i) if (r >= base[i + 1]) e = i + 1;
    const int tok = slots[e * N_TOK + (r - base[e])];
    const float* src = X + (size_t)tok * DIM + lane * 16;
    unsigned short* dst = Xp + (size_t)r * DIM + lane * 16;
    f32x4 v0 = *(const f32x4*)(src);
    f32x4 v1 = *(const f32x4*)(src + 4);
    f32x4 v2 = *(const f32x4*)(src + 8);
    f32x4 v3 = *(const f32x4*)(src + 12);
    unsigned short t0[8], t1[8];
#pragma unroll
    for (int i = 0; i < 4; ++i) { t0[i] = f2bf(v0[i]); t0[4 + i] = f2bf(v1[i]); }
#pragma unroll
    for (int i = 0; i < 4; ++i) { t1[i] = f2bf(v2[i]); t1[4 + i] = f2bf(v3[i]); }
    *(s16x8*)(dst)     = *(const s16x8*)t0;
    *(s16x8*)(dst + 8) = *(const s16x8*)t1;
}

// 1 block/CU, 8 waves, 256-VGPR cap: acc[2][4][4]=128 f32 + bv[8]=32 + addr fits
// with NO spill (round 6's (512,4) capped VGPR at 64 -> 1.3 GB scratch traffic).
__global__ __launch_bounds__(NTHR, 2) void k_gemm(
        const float* __restrict__ W, const int* __restrict__ counts,
        const int* __restrict__ base, const unsigned short* __restrict__ slots,
        const unsigned short* __restrict__ Xp, float* __restrict__ out) {
    // XCD-paired 1-D grid: id = rt*NPAIR + (e*CT_TILES+ct); id%8 == ct%8, so all
    // row-tiles of one (e,ct) land on the SAME XCD; rt=0 (ids 0..127) and rt=1
    // (ids 128..255) are co-resident -> shared W-tile stream stays L2-resident.
    const int bid = blockIdx.x;
    const int p   = bid & (NPAIR - 1);
    const int rt  = bid >> 7;           // log2(NPAIR)=7
    const int e   = p >> 4;             // log2(CT_TILES)=4
    const int ct  = p & (CT_TILES - 1);
    const int cnt = counts[e];
    const int tbase = rt * BM;
    if (tbase >= cnt) return;

    // As: [row][k] bf16, slot = q ^ (row&7), written via pre-swizzled global src +
    // linear global_load_lds. Bs: [col][k] bf16 transposed W, slot = ko ^ key(c).
    // Both single-buffered: 32 KiB + 32 KiB = 64 KiB.
    __shared__ unsigned short As[BM * BK];
    __shared__ unsigned short Bs[2 * BN * BK];

    const int t    = threadIdx.x;
    const int lane = t & 63;
    const int wid  = t >> 6;            // 0..7
    const int wm   = wid >> 1;          // wave row 0..3 (64 rows each)
    const int wn   = wid & 1;           // wave col 0..1 (64 out-cols each)
    const int l16  = lane & 15;
    const int g16  = lane >> 4;

    // ---- A staging via global_load_lds: 4 instrs/thread, pre-swizzled source ----
    const unsigned short* aptr[4];
#pragma unroll
    for (int j = 0; j < 4; ++j) {
        int i  = wid * 4 + j;                       // 0..31 chunks of 1 KiB
        int rl = i * 8 + (lane >> 3);               // tile row 0..255
        int qs = (lane & 7) ^ ((lane >> 3) & 7);    // pre-swizzled k-granule
        int slot = tbase + rl;
        aptr[j] = Xp + (size_t)(base[e] + min(slot, cnt - 1)) * DIM + qs * 8;
    }
    // ---- B staging: per 256-thread half, cols 0..127 / 128..255; 8 dwordx4 ----
    const int c0 = (t & 31) * 4 + ((t >> 8) & 1) * 128;   // local col, 4 per thread
    const int ko = (t >> 5) & 7;                          // k-octet 0..7
    const int gcol = ct * BN + (c0 & 127) + (c0 >> 7) * HV;  // gate cols / up cols
    const float* bptr = W + (size_t)e * DIM * H2V + (size_t)(ko * 8) * H2V + gcol;

    f32x4 acc[2][4][4];
    const f32x4 zero = {0.f, 0.f, 0.f, 0.f};
#pragma unroll
    for (int g = 0; g < 2; ++g)
#pragma unroll
        for (int m = 0; m < 4; ++m)
#pragma unroll
            for (int n = 0; n < 4; ++n) acc[g][m][n] = zero;

    f32x4 bv[8];                        // single B register set (no spill)

    auto issueA = [&](int ks) {
#pragma unroll
        for (int j = 0; j < 4; ++j) {
            const unsigned short* g = aptr[j] + ks * BK;
            unsigned short* l = (unsigned short*)&As[(wid * 4 + j) * 512];
            __builtin_amdgcn_global_load_lds(
                (const __attribute__((address_space(1))) unsigned int*)(const void*)g,
                (__attribute__((address_space(3))) unsigned int*)(void*)l, 16, 0, 0);
        }
    };
    auto loadB = [&](int ks) {
#pragma unroll
        for (int i = 0; i < 8; ++i)
            bv[i] = *(const f32x4*)(bptr + (size_t)(ks * BK + i) * H2V);
    };
    auto storeB = [&]() {
#pragma unroll
        for (int j = 0; j < 4; ++j) {
            int c = c0 + j;
            int key = ((c >> 1) ^ (c >> 4)) & 7;
            unsigned short tmp[8];
#pragma unroll
            for (int i = 0; i < 8; ++i) tmp[i] = f2bf(bv[i][j]);
            *(s16x8*)&Bs[c * 64 + ((ko ^ key) * 8)] = *(const s16x8*)tmp;
        }
    };
    auto mfmaPhase = [&]() {
        __builtin_amdgcn_s_setprio(1);
#pragma unroll
        for (int kk = 0; kk < 2; ++kk) {
            const int gran = kk * 4 + g16;
            s16x8 af[4], bfr[2][4];
#pragma unroll
            for (int m = 0; m < 4; ++m) {
                int row = wm * 64 + m * 16 + l16;
                af[m] = *(const s16x8*)&As[row * 64 + ((gran ^ (row & 7)) * 8)];
            }
#pragma unroll
            for (int g = 0; g < 2; ++g)
#pragma unroll
                for (int n = 0; n < 4; ++n) {
                    int c = g * 128 + wn * 64 + n * 16 + l16;
                    int key = ((c >> 1) ^ (c >> 4)) & 7;
                    bfr[g][n] = *(const s16x8*)&Bs[c * 64 + ((gran ^ key) * 8)];
                }
#pragma unroll
            for (int g = 0; g < 2; ++g)
#pragma unroll
                for (int m = 0; m < 4; ++m)
#pragma unroll
                    for (int n = 0; n < 4; ++n)
                        acc[g][m][n] = __builtin_amdgcn_mfma_f32_16x16x32_bf16(
                            af[m], bfr[g][n], acc[g][m][n], 0, 0, 0);
        }
        __builtin_amdgcn_s_setprio(0);
    };

    // ---- prologue: A(0)+B(0) in flight; stage both; start B(1) ----
    issueA(0);
    loadB(0);
    asm volatile("s_waitcnt vmcnt(0)" ::: "memory");
    __builtin_amdgcn_sched_barrier(0);
    storeB();
    loadB(1);                           // 8 loads in flight across iter 0's MFMA
    asm volatile("s_waitcnt lgkmcnt(0)" ::: "memory");
    __builtin_amdgcn_sched_barrier(0);
    __builtin_amdgcn_s_barrier();

    // ---- main loop (single-buffered As/Bs; counted vmcnt, no mid-loop drain) ----
    // top-of-iter state: As=A(ks), Bs=B(ks) valid; B(ks+1)[8] in flight.
#pragma unroll 1
    for (int ks = 0; ks < KSTEPS; ++ks) {
        mfmaPhase();
        if (ks + 1 < KSTEPS) {
            __builtin_amdgcn_s_barrier();                      // all reads of As/Bs done
            issueA(ks + 1);                                    // 4 gll -> As
            asm volatile("s_waitcnt vmcnt(4)" ::: "memory");   // B(ks+1) regs landed
            __builtin_amdgcn_sched_barrier(0);
            storeB();                                          // -> Bs
            if (ks + 2 < KSTEPS) {
                loadB(ks + 2);                                 // window: barrier+mfma
                asm volatile("s_waitcnt vmcnt(8) lgkmcnt(0)" ::: "memory"); // A(ks+1) done
            } else {
                asm volatile("s_waitcnt vmcnt(0) lgkmcnt(0)" ::: "memory"); // tail: drain A
            }
            __builtin_amdgcn_sched_barrier(0);
            __builtin_amdgcn_s_barrier();                      // staging visible
        }
    }

    // epilogue: silu(gate) * up, scatter rows to token ids
    const unsigned short* ids = slots + e * N_TOK;
#pragma unroll
    for (int m = 0; m < 4; ++m) {
#pragma unroll
        for (int r = 0; r < 4; ++r) {
            int rowt = wm * 64 + m * 16 + g16 * 4 + r;         // C/D: row=(lane>>4)*4+r
            int slot = tbase + rowt;
            if (slot < cnt) {
                int tok = ids[slot];
#pragma unroll
                for (int n = 0; n < 4; ++n) {
                    int col = ct * BN + wn * 64 + n * 16 + l16;  // C/D: col=lane&15
                    float a = acc[0][m][n][r];
                    float b = acc[1][m][n][r];
                    float sg = a / (1.0f + __expf(-a));
                    out[(size_t)tok * HV + col] = sg * b;
                }
            }
        }
    }
}

extern "C" void kernel_launch(void* const* d_in, const int* in_sizes, int n_in,
                              void* d_out, int out_size, void* d_ws, size_t ws_size,
                              hipStream_t stream) {
    const float* X  = (const float*)d_in[0];
    const float* W  = (const float*)d_in[1];
    const int* idx  = (const int*)d_in[2];
    float* out      = (float*)d_out;

    int* counts = (int*)((char*)d_ws + WS_COUNTS);
    int* base   = (int*)((char*)d_ws + WS_BASE);
    unsigned short* slots = (unsigned short*)((char*)d_ws + WS_SLOTS);
    unsigned short* Xp    = (unsigned short*)((char*)d_ws + WS_XPERM);

    k_init<<<1, 64, 0, stream>>>(counts);
    k_scatter<<<N_TOK / 256, 256, 0, stream>>>(idx, counts, slots);
    k_base<<<1, 64, 0, stream>>>(counts, base);
    k_gather<<<N_TOK / 4, 256, 0, stream>>>(X, base, slots, Xp);
    k_gemm<<<RT_SLOTS * NPAIR, NTHR, 0, stream>>>(W, counts, base, slots, Xp, out);
}